// Round 1
// baseline (347.756 us; speedup 1.0000x reference)
//
#include <hip/hip_runtime.h>

#define L  2048
#define D  64
#define NH 16
#define NB 2

using half8   = _Float16 __attribute__((ext_vector_type(8)));
using half4v  = _Float16 __attribute__((ext_vector_type(4)));
using float4v = float    __attribute__((ext_vector_type(4)));

// ---------------- precompute: qh = fp16(q/8), kh = fp16(k) ----------------
__global__ __launch_bounds__(256) void prep_qk(const float* __restrict__ q,
                                               const float* __restrict__ k,
                                               _Float16* __restrict__ qh,
                                               _Float16* __restrict__ kh) {
    int i = (blockIdx.x * 256 + threadIdx.x) * 8;
    float4v a0 = *(const float4v*)(q + i);
    float4v a1 = *(const float4v*)(q + i + 4);
    float4v b0 = *(const float4v*)(k + i);
    float4v b1 = *(const float4v*)(k + i + 4);
    half8 qo, ko;
#pragma unroll
    for (int j = 0; j < 4; ++j) {
        qo[j]     = (_Float16)(a0[j] * 0.125f);   // fold 1/TEMPERATURE
        qo[4 + j] = (_Float16)(a1[j] * 0.125f);
        ko[j]     = (_Float16)b0[j];
        ko[4 + j] = (_Float16)b1[j];
    }
    *(half8*)(qh + i) = qo;
    *(half8*)(kh + i) = ko;
}

// ---------------- precompute: vt[b,h,d,l] = fp16(v[b,h,l,d]) ----------------
__global__ __launch_bounds__(256) void prep_vt(const float* __restrict__ v,
                                               _Float16* __restrict__ vt) {
    __shared__ float tile[64][65];
    int bh = blockIdx.x >> 5;          // 0..31
    int l0 = (blockIdx.x & 31) * 64;
    const float* vb = v + (size_t)bh * L * D + (size_t)l0 * D;
    int row = threadIdx.x >> 2, c0 = (threadIdx.x & 3) * 16;
#pragma unroll
    for (int j = 0; j < 16; j += 4) {
        float4v t4 = *(const float4v*)(vb + row * D + c0 + j);
        tile[row][c0 + j + 0] = t4[0];
        tile[row][c0 + j + 1] = t4[1];
        tile[row][c0 + j + 2] = t4[2];
        tile[row][c0 + j + 3] = t4[3];
    }
    __syncthreads();
    int d = threadIdx.x >> 2, lq = (threadIdx.x & 3) * 16;
    _Float16* ob = vt + (size_t)bh * D * L + (size_t)d * L + l0 + lq;
    half8 o0, o1;
#pragma unroll
    for (int j = 0; j < 8; ++j) {
        o0[j] = (_Float16)tile[lq + j][d];
        o1[j] = (_Float16)tile[lq + 8 + j][d];
    }
    *(half8*)(ob)     = o0;
    *(half8*)(ob + 8) = o1;
}

// ---------------- precompute: mb = mask ? bias : -1e9 ----------------
__global__ __launch_bounds__(256) void prep_mb(const int* __restrict__ mask,
                                               const float* __restrict__ bias,
                                               float* __restrict__ mb) {
    int i = (blockIdx.x * 256 + threadIdx.x) * 8;
#pragma unroll
    for (int j = 0; j < 8; j += 4) {
        int4    m  = *(const int4*)(mask + i + j);
        float4v bv = *(const float4v*)(bias + i + j);
        float4v o;
        o[0] = m.x ? bv[0] : -1e9f;
        o[1] = m.y ? bv[1] : -1e9f;
        o[2] = m.z ? bv[2] : -1e9f;
        o[3] = m.w ? bv[3] : -1e9f;
        *(float4v*)(mb + i + j) = o;
    }
}

// ---------------- main attention kernel ----------------
// block = (b, h, qtile of 16 rows), 256 threads = 4 waves.
// wave w computes scores for keys [512w, 512w+512); exp(s) kept in 128 VGPRs.
template <bool USE_MB>
__global__ __launch_bounds__(256, 2) void attn_main(const _Float16* __restrict__ qh,
                                                    const _Float16* __restrict__ kh,
                                                    const _Float16* __restrict__ vt,
                                                    const float* __restrict__ mb,
                                                    const int* __restrict__ mask,
                                                    const float* __restrict__ bias,
                                                    float* __restrict__ out_ho,
                                                    float* __restrict__ out_attn) {
    constexpr int PSTR = 2056;               // fp16 elems per P row (pad: dword stride = 4 mod 32)
    __shared__ _Float16 P[16 * PSTR];        // 65792 B (gfx950 allows >64KB LDS)
    __shared__ float lpart[4][16];
    __shared__ float rls[16];

    // XCD-chunked swizzle (hw xcd = blockIdx % 8): each XCD owns 4 heads -> K/V stay L2-resident.
    int p  = blockIdx.x;
    int l  = (p & 7) * 512 + (p >> 3);
    int h1 = l & 3, qt = (l >> 2) & 127, h2 = (l >> 9) & 3, b = l >> 11;
    int h  = h2 * 4 + h1;
    int bh = b * NH + h;
    int q0 = qt * 16;

    int tid  = threadIdx.x;
    int w    = tid >> 6, lane = tid & 63;
    int cg   = lane & 15;     // frag col (key for QK; q-row for PV-A; d for PV-B)
    int grp  = lane >> 4;     // 0..3

    const _Float16* qbase = qh + ((size_t)bh * L + q0) * D;
    const _Float16* kbase = kh + (size_t)bh * L * D;
    const _Float16* vbase = vt + (size_t)bh * D * L;

    // A-frags (Q rows), K-dim chunks 0/1
    half8 aq0 = *(const half8*)(qbase + cg * D + grp * 8);
    half8 aq1 = *(const half8*)(qbase + cg * D + 32 + grp * 8);

    float4v pu[32];
    float ls0 = 0.f, ls1 = 0.f, ls2 = 0.f, ls3 = 0.f;
    int k0w = w * 512;
#pragma unroll
    for (int f = 0; f < 32; ++f) {
        int n0 = k0w + f * 16;
        const _Float16* kb = kbase + (size_t)(n0 + cg) * D + grp * 8;
        half8 bk0 = *(const half8*)(kb);
        half8 bk1 = *(const half8*)(kb + 32);
        float4v acc;
        if constexpr (USE_MB) {
            const float* mrow = mb + ((size_t)b * L + q0) * L + n0 + cg;
            acc[0] = mrow[(size_t)(grp * 4 + 0) * L];
            acc[1] = mrow[(size_t)(grp * 4 + 1) * L];
            acc[2] = mrow[(size_t)(grp * 4 + 2) * L];
            acc[3] = mrow[(size_t)(grp * 4 + 3) * L];
        } else {
            size_t base = ((size_t)b * L + q0) * L + n0 + cg;
#pragma unroll
            for (int r = 0; r < 4; ++r) {
                int   mm = mask[base + (size_t)(grp * 4 + r) * L];
                float bb = bias[base + (size_t)(grp * 4 + r) * L];
                acc[r] = mm ? bb : -1e9f;
            }
        }
        acc = __builtin_amdgcn_mfma_f32_16x16x32_f16(aq0, bk0, acc, 0, 0, 0);
        acc = __builtin_amdgcn_mfma_f32_16x16x32_f16(aq1, bk1, acc, 0, 0, 0);
        float4v e;
        e[0] = __expf(acc[0]); e[1] = __expf(acc[1]);
        e[2] = __expf(acc[2]); e[3] = __expf(acc[3]);
        ls0 += e[0]; ls1 += e[1]; ls2 += e[2]; ls3 += e[3];
        pu[f] = e;
    }

    // reduce l over the 16 key-cols held by this 16-lane group
#pragma unroll
    for (int m = 1; m < 16; m <<= 1) {
        ls0 += __shfl_xor(ls0, m);
        ls1 += __shfl_xor(ls1, m);
        ls2 += __shfl_xor(ls2, m);
        ls3 += __shfl_xor(ls3, m);
    }
    if (cg == 0) {
        lpart[w][grp * 4 + 0] = ls0;
        lpart[w][grp * 4 + 1] = ls1;
        lpart[w][grp * 4 + 2] = ls2;
        lpart[w][grp * 4 + 3] = ls3;
    }
    __syncthreads();
    if (tid < 16) {
        float s = lpart[0][tid] + lpart[1][tid] + lpart[2][tid] + lpart[3][tid];
        rls[tid] = 1.0f / s;
    }
    __syncthreads();

    // normalize and store P (fp16) to LDS
    float rl0 = rls[grp * 4 + 0], rl1 = rls[grp * 4 + 1];
    float rl2 = rls[grp * 4 + 2], rl3 = rls[grp * 4 + 3];
#pragma unroll
    for (int f = 0; f < 32; ++f) {
        int col = k0w + f * 16 + cg;
        P[(grp * 4 + 0) * PSTR + col] = (_Float16)(pu[f][0] * rl0);
        P[(grp * 4 + 1) * PSTR + col] = (_Float16)(pu[f][1] * rl1);
        P[(grp * 4 + 2) * PSTR + col] = (_Float16)(pu[f][2] * rl2);
        P[(grp * 4 + 3) * PSTR + col] = (_Float16)(pu[f][3] * rl3);
    }
    __syncthreads();

    // coalesced attn write: 16 x 2048 fp32
    float* abase = out_attn + ((size_t)bh * L + q0) * L;
#pragma unroll 4
    for (int i = 0; i < 32; ++i) {
        int c4  = i * 256 + tid;        // 0..8191 float4-chunks
        int row = c4 >> 9;              // 512 chunks per row
        int col = (c4 & 511) * 4;
        half4v p4 = *(const half4v*)(&P[row * PSTR + col]);
        float4v o;
        o[0] = (float)p4[0]; o[1] = (float)p4[1];
        o[2] = (float)p4[2]; o[3] = (float)p4[3];
        *(float4v*)(abase + (size_t)row * L + col) = o;
    }

    // PV: wave w owns d-slice [16w, 16w+16), full K range from LDS P
    int d0 = w * 16;
    float4v oacc = {0.f, 0.f, 0.f, 0.f};
    for (int kc = 0; kc < 64; ++kc) {
        half8 pa = *(const half8*)(&P[cg * PSTR + kc * 32 + grp * 8]);
        half8 pb = *(const half8*)(vbase + (size_t)(d0 + cg) * L + kc * 32 + grp * 8);
        oacc = __builtin_amdgcn_mfma_f32_16x16x32_f16(pa, pb, oacc, 0, 0, 0);
    }
    float* obase = out_ho + ((size_t)bh * L + q0) * D + d0;
    obase[(size_t)(grp * 4 + 0) * D + cg] = oacc[0];
    obase[(size_t)(grp * 4 + 1) * D + cg] = oacc[1];
    obase[(size_t)(grp * 4 + 2) * D + cg] = oacc[2];
    obase[(size_t)(grp * 4 + 3) * D + cg] = oacc[3];
}

extern "C" void kernel_launch(void* const* d_in, const int* in_sizes, int n_in,
                              void* d_out, int out_size, void* d_ws, size_t ws_size,
                              hipStream_t stream) {
    const float* q    = (const float*)d_in[0];
    const float* k    = (const float*)d_in[1];
    const float* v    = (const float*)d_in[2];
    const int*   mask = (const int*)d_in[3];
    const float* bias = (const float*)d_in[4];

    float* ho   = (float*)d_out;
    float* attn = (float*)d_out + (size_t)NB * NH * L * D;

    char* ws = (char*)d_ws;
    _Float16* qh = (_Float16*)(ws);                       // 8 MB
    _Float16* kh = (_Float16*)(ws + ((size_t)8  << 20));  // 8 MB
    _Float16* vt = (_Float16*)(ws + ((size_t)16 << 20));  // 8 MB
    float*    mb = (float*)   (ws + ((size_t)24 << 20));  // 32 MB (optional)

    const size_t need_base = (size_t)24 << 20;
    const size_t need_mb   = need_base + (size_t)NB * L * L * sizeof(float);
    bool use_mb = (ws_size >= need_mb);
    (void)in_sizes; (void)n_in; (void)out_size; (void)need_base;

    prep_qk<<<2048, 256, 0, stream>>>(q, k, qh, kh);
    prep_vt<<<1024, 256, 0, stream>>>(v, vt);
    if (use_mb) {
        prep_mb<<<4096, 256, 0, stream>>>(mask, bias, mb);
        attn_main<true><<<4096, 256, 0, stream>>>(qh, kh, vt, mb, nullptr, nullptr, ho, attn);
    } else {
        attn_main<false><<<4096, 256, 0, stream>>>(qh, kh, vt, nullptr, mask, bias, ho, attn);
    }
}